// Round 16
// baseline (336.442 us; speedup 1.0000x reference)
//
#include <hip/hip_runtime.h>

#define CIN 16
#define HH 256
#define WW 256
#define HID 128
#define KEFF 144        // 9 taps * 16 channels
#define WS_BYTES (HID * KEFF * 2 + CIN * HID * 2)   // 36864 + 4096 = 40960

typedef short short8b __attribute__((ext_vector_type(8)));
typedef float f32x4 __attribute__((ext_vector_type(4)));

// fp32 -> bf16 round-to-nearest-even (finite inputs)
__device__ __forceinline__ unsigned short f2bf(float f) {
    union { float f; unsigned int u; } v; v.f = f;
    unsigned int u = v.u;
    return (unsigned short)((u + 0x7fffu + ((u >> 16) & 1u)) >> 16);
}

// Pre-kernel: Weff[o][tap][c] = W1[o][c]*d(tap==4) + W1[o][16+c]*Sx + W1[o][32+c]*Sy ; then w2 bf16.
__global__ __launch_bounds__(256) void build_weff(
    const float* __restrict__ w1, const float* __restrict__ w2,
    unsigned short* __restrict__ ws)
{
    const float SX[9] = {-1.f, 0.f, 1.f, -2.f, 0.f, 2.f, -1.f, 0.f, 1.f};
    const float SY[9] = {-1.f, -2.f, -1.f, 0.f, 0.f, 0.f, 1.f, 2.f, 1.f};
    const int idx = blockIdx.x * 256 + threadIdx.x;
    if (idx < HID * KEFF) {
        const int o = idx / KEFF, r = idx % KEFF;
        const int tap = r >> 4, c = r & 15;
        float v = w1[o * 48 + 16 + c] * SX[tap] + w1[o * 48 + 32 + c] * SY[tap];
        if (tap == 4) v += w1[o * 48 + c];
        ws[idx] = f2bf(v);
    } else if (idx < HID * KEFF + CIN * HID) {
        ws[idx] = f2bf(w2[idx - HID * KEFF]);
    }
}

// v12 LDS carve (bytes):
//   xl   : [0, 19584)        [34][18][16] bf16 channel-last, 32 B/pixel
//   hbuf : [19584, 35968)    [2 p][2 phase][16 px][256 B], XOR-swizzled
//   zreg : [35968, 36000)    32 B zeros
#define SMC_XL  0
#define SMC_HB  19584
#define SMC_ZR  35968
#define SMC_TOT 36000

// v8's per-row pipeline + S=4 row amortization of A-fragment acquisition.
// Measured fact (r5/r7/r8/r15): hipcc ALWAYS remats wave-invariant weight-frag
// loads into barriered loops — residency is unobtainable; total A-stream was
// ~5.2 GB and pinned profiled time at ~273 us in every per-row variant.
// v12 loads A once per 4-row super-iteration inside the k-loop (remat target
// IS the intended placement): A-traffic /4 -> ~1.3 GB, hidden under 16 MFMAs
// per {4 A + 4 B} load group. acc[4 mt][4 s] = 64 accumulators (AGPR) — half
// of v9's 128 that collapsed occupancy. Epilogue = proven v8 h-exchange.
__global__ __launch_bounds__(256, 3) void updatenet_v12(
    const float* __restrict__ x,             // [B,16,256,256]
    const unsigned short* __restrict__ ws,   // bf16 weff[128][144] + w2[16][128]
    float* __restrict__ out)                 // [B,16,256,256]
{
    __shared__ __align__(16) unsigned char smem[SMC_TOT];
    unsigned short* xl   = (unsigned short*)(smem + SMC_XL);
    unsigned short* zreg = (unsigned short*)(smem + SMC_ZR);

    const int b  = blockIdx.z;
    const int i0 = blockIdx.y * 32;
    const int j0 = blockIdx.x * 16;
    const int t  = threadIdx.x;     // 0..255

    // ---- stage x tile 34x18 (channel-last bf16, zero-pad OOB) ----
    {
        const size_t cs = (size_t)HH * WW;
        for (int pidx = t; pidx < 34 * 18; pidx += 256) {
            const int ri = pidx / 18, rj = pidx % 18;
            const int ii = i0 + ri - 1, jj = j0 + rj - 1;
            const bool ok = (ii >= 0) & (ii < HH) & (jj >= 0) & (jj < WW);
            const float* xp = x + ((size_t)b * CIN * HH + ii) * WW + jj;
            short8b s0, s1;
            #pragma unroll
            for (int c = 0; c < 8; ++c) {
                s0[c] = ok ? (short)f2bf(xp[c * cs]) : (short)0;
                s1[c] = ok ? (short)f2bf(xp[(c + 8) * cs]) : (short)0;
            }
            *(short8b*)(xl + pidx * 16)     = s0;
            *(short8b*)(xl + pidx * 16 + 8) = s1;
        }
        if (t < 2) *(short8b*)(zreg + t * 8) = (short8b)0;
    }

    const int wv   = t >> 6;        // 0..3
    const int lane = t & 63;
    const int p    = wv >> 1;       // pixel half: rows 16p..16p+15
    const int q    = wv & 1;        // o half: o in [64q, 64q+64)
    const int g    = lane >> 4;     // k-group 0..3
    const int nn   = lane & 15;     // MFMA row/col-in-tile
    const int gh   = g >> 1, gl = g & 1;

    // per-lane tap byte-offsets into xl: tap = 2ks+gh, (di,dj) = (tap/3, tap%3)
    int off[5];
    #pragma unroll
    for (int ks = 0; ks < 5; ++ks) {
        int tap = 2 * ks + gh;
        if (tap > 8) tap = 8;       // ks=4,gh=1 -> B redirected to zreg
        off[ks] = ((tap / 3) * 18 + (tap % 3)) * 32 + gl * 16;
    }

    unsigned char* hb_pair = smem + SMC_HB + p * 8192;   // 2 phases x 16 x 256 B
    const int xmask = (nn & 7) << 4;                      // hbuf XOR swizzle

    __syncthreads();

    // ---- 4 super-iterations of 4 rows each ----
    for (int sup = 0; sup < 4; ++sup) {
        const int r0 = 16 * p + 4 * sup;

        // layer-1, k-outer over 4 rows: acc[mt][s] (64 f32, AGPR-resident)
        f32x4 acc[4][4];
        #pragma unroll
        for (int mt = 0; mt < 4; ++mt)
            #pragma unroll
            for (int s = 0; s < 4; ++s) acc[mt][s] = (f32x4)0.f;

        #pragma unroll
        for (int ks = 0; ks < 5; ++ks) {
            short8b Bf[4];
            #pragma unroll
            for (int s = 0; s < 4; ++s) {
                const unsigned char* bp = (ks == 4 && gh)
                    ? (const unsigned char*)(zreg + gl * 8)
                    : (const unsigned char*)xl + ((r0 + s) * 18 + nn) * 32 + off[ks];
                Bf[s] = *(const short8b*)bp;
            }
            // ks<4: k = 32ks+8g. ks=4: k = 128+8*gl (payload for g=0,1; g>=2
            // reads in-row data x zero-B — never leaves its 144-elem row).
            const int ak = (ks == 4) ? (128 + 8 * gl) : (32 * ks + 8 * g);
            #pragma unroll
            for (int mt = 0; mt < 4; ++mt) {
                const short8b Af = *(const short8b*)(ws + (size_t)(64 * q + 16 * mt + nn) * KEFF + ak);
                #pragma unroll
                for (int s = 0; s < 4; ++s)
                    acc[mt][s] = __builtin_amdgcn_mfma_f32_16x16x32_bf16(Af, Bf[s], acc[mt][s], 0, 0, 0);
            }
        }

        // epilogue: 4 rows of h-exchange (dbuf) + alternating layer-2 worker
        #pragma unroll
        for (int s = 0; s < 4; ++s) {
            const int row = r0 + s;
            unsigned char* hph = hb_pair + (s & 1) * 4096;
            #pragma unroll
            for (int mt = 0; mt < 4; ++mt) {
                const unsigned int lo = (unsigned int)f2bf(fmaxf(acc[mt][s][0], 0.f))
                                      | ((unsigned int)f2bf(fmaxf(acc[mt][s][1], 0.f)) << 16);
                const unsigned int hi = (unsigned int)f2bf(fmaxf(acc[mt][s][2], 0.f))
                                      | ((unsigned int)f2bf(fmaxf(acc[mt][s][3], 0.f)) << 16);
                uint2 u; u.x = lo; u.y = hi;
                const int wb = (nn << 8) + ((64 * q + 16 * mt + 4 * g) << 1);
                *(uint2*)(hph + (wb ^ xmask)) = u;
            }

            __syncthreads();   // h(row) visible; phase reuse fenced by next barrier

            if (q == (s & 1)) {
                f32x4 a2 = (f32x4)0.f;
                #pragma unroll
                for (int ks2 = 0; ks2 < 4; ++ks2) {
                    const short8b aw2 = *(const short8b*)(ws + HID * KEFF + nn * HID + 32 * ks2 + 8 * g);
                    const int rb = (nn << 8) + ((32 * ks2 + 8 * g) << 1);
                    const short8b bh = *(const short8b*)(hph + (rb ^ xmask));
                    a2 = __builtin_amdgcn_mfma_f32_16x16x32_bf16(aw2, bh, a2, 0, 0, 0);
                }
                const int oi = i0 + row, oj = j0 + nn;
                float* op = out + ((size_t)(b * CIN + 4 * g) * HH + oi) * WW + oj;
                #pragma unroll
                for (int r = 0; r < 4; ++r)
                    op[(size_t)r * HH * WW] = a2[r];
            }
        }
    }
}

// ---------- fallback (no usable ws): proven round-4 kernel ----------
#define SM_WEFF  0
#define SM_GUARD 36864
#define SM_W2B   36880
#define SM_XL    41232
#define SM_ZREG  60816
#define SM_HALL  60848
#define SM_TOTAL 78256

__global__ __launch_bounds__(256, 2) void updatenet_fallback(
    const float* __restrict__ x, const float* __restrict__ w1f,
    const float* __restrict__ w2f, float* __restrict__ out)
{
    __shared__ __align__(16) unsigned char smem[SM_TOTAL];
    unsigned short* weff = (unsigned short*)(smem + SM_WEFF);
    unsigned short* w2b  = (unsigned short*)(smem + SM_W2B);
    unsigned short* xl   = (unsigned short*)(smem + SM_XL);
    unsigned short* zreg = (unsigned short*)(smem + SM_ZREG);

    const int b  = blockIdx.z;
    const int i0 = blockIdx.y * 32;
    const int j0 = blockIdx.x * 16;
    const int t  = threadIdx.x;

    for (int idx = t; idx < HID * KEFF; idx += 256) {
        const float SX[9] = {-1.f, 0.f, 1.f, -2.f, 0.f, 2.f, -1.f, 0.f, 1.f};
        const float SY[9] = {-1.f, -2.f, -1.f, 0.f, 0.f, 0.f, 1.f, 2.f, 1.f};
        const int o = idx / KEFF, r = idx % KEFF;
        const int tap = r >> 4, cc = r & 15;
        float v = w1f[o * 48 + 16 + cc] * SX[tap] + w1f[o * 48 + 32 + cc] * SY[tap];
        if (tap == 4) v += w1f[o * 48 + cc];
        weff[idx] = f2bf(v);
    }
    for (int idx = t; idx < CIN * HID; idx += 256)
        w2b[(idx >> 7) * 136 + (idx & 127)] = f2bf(w2f[idx]);

    {
        const size_t cs = (size_t)HH * WW;
        for (int pp = t; pp < 34 * 18; pp += 256) {
            const int ri = pp / 18, rj = pp % 18;
            const int ii = i0 + ri - 1, jj = j0 + rj - 1;
            const bool ok = (ii >= 0) & (ii < HH) & (jj >= 0) & (jj < WW);
            const float* xp = x + ((size_t)b * CIN * HH + ii) * WW + jj;
            short8b s0, s1;
            #pragma unroll
            for (int c = 0; c < 8; ++c) {
                s0[c] = ok ? (short)f2bf(xp[c * cs]) : (short)0;
                s1[c] = ok ? (short)f2bf(xp[(c + 8) * cs]) : (short)0;
            }
            *(short8b*)(xl + pp * 16)     = s0;
            *(short8b*)(xl + pp * 16 + 8) = s1;
        }
        if (t < 2) *(short8b*)(zreg + t * 8) = (short8b)0;
        if (t == 2) *(short8b*)(smem + SM_GUARD) = (short8b)0;
    }
    __syncthreads();

    const int w = t >> 6, lane = t & 63;
    const int g = lane >> 4, nn = lane & 15;
    const int gh = g >> 1, gl = g & 1;

    short8b aW1[8][5];
    #pragma unroll
    for (int m = 0; m < 8; ++m)
        #pragma unroll
        for (int ks = 0; ks < 5; ++ks) {
            const int ak = (ks == 4) ? (128 + 8 * gl) : (32 * ks + 8 * g);
            aW1[m][ks] = *(const short8b*)(weff + (16 * m + nn) * KEFF + ak);
        }

    int off[5];
    #pragma unroll
    for (int ks = 0; ks < 5; ++ks) {
        int tap = 2 * ks + gh;
        if (tap > 8) tap = 8;
        off[ks] = ((tap / 3) * 18 + (tap % 3)) * 32 + gl * 16;
    }

    unsigned short* hb = (unsigned short*)(smem + SM_HALL) + w * (16 * 136);

    for (int nt = 0; nt < 8; ++nt) {
        const int i = 8 * w + nt;
        const unsigned char* xbase = (const unsigned char*)xl + (i * 18 + nn) * 32;
        f32x4 acc[8];
        #pragma unroll
        for (int m = 0; m < 8; ++m) acc[m] = (f32x4)0.f;
        #pragma unroll
        for (int ks = 0; ks < 5; ++ks) {
            const unsigned char* bp = (ks == 4 && gh) ? (const unsigned char*)(zreg + gl * 8)
                                                      : xbase + off[ks];
            const short8b bfrag = *(const short8b*)bp;
            #pragma unroll
            for (int m = 0; m < 8; ++m)
                acc[m] = __builtin_amdgcn_mfma_f32_16x16x32_bf16(aW1[m][ks], bfrag, acc[m], 0, 0, 0);
        }
        #pragma unroll
        for (int m = 0; m < 8; ++m) {
            const unsigned int lo = (unsigned int)f2bf(fmaxf(acc[m][0], 0.f))
                                  | ((unsigned int)f2bf(fmaxf(acc[m][1], 0.f)) << 16);
            const unsigned int hi = (unsigned int)f2bf(fmaxf(acc[m][2], 0.f))
                                  | ((unsigned int)f2bf(fmaxf(acc[m][3], 0.f)) << 16);
            uint2 u; u.x = lo; u.y = hi;
            *(uint2*)(hb + nn * 136 + 16 * m + 4 * g) = u;
        }
        asm volatile("s_waitcnt lgkmcnt(0)" ::: "memory");
        f32x4 a2 = (f32x4)0.f;
        #pragma unroll
        for (int ks = 0; ks < 4; ++ks) {
            const short8b aw2 = *(const short8b*)(w2b + nn * 136 + 32 * ks + 8 * g);
            const short8b bh  = *(const short8b*)(hb + nn * 136 + 32 * ks + 8 * g);
            a2 = __builtin_amdgcn_mfma_f32_16x16x32_bf16(aw2, bh, a2, 0, 0, 0);
        }
        const int oi = i0 + i, oj = j0 + nn;
        float* op = out + ((size_t)(b * CIN + 4 * g) * HH + oi) * WW + oj;
        #pragma unroll
        for (int r = 0; r < 4; ++r)
            op[(size_t)r * HH * WW] = a2[r];
    }
}

extern "C" void kernel_launch(void* const* d_in, const int* in_sizes, int n_in,
                              void* d_out, int out_size, void* d_ws, size_t ws_size,
                              hipStream_t stream) {
    const float* x  = (const float*)d_in[0];
    const float* w1 = (const float*)d_in[1];
    const float* w2 = (const float*)d_in[2];
    float* out = (float*)d_out;

    const int Bn = in_sizes[0] / (CIN * HH * WW);   // 32
    dim3 grid(WW / 16, HH / 32, Bn);                // 16 x 8 x 32 = 4096 blocks

    if (ws_size >= (size_t)WS_BYTES) {
        unsigned short* ws = (unsigned short*)d_ws;
        build_weff<<<(HID * KEFF + CIN * HID + 255) / 256, 256, 0, stream>>>(w1, w2, ws);
        updatenet_v12<<<grid, 256, 0, stream>>>(x, ws, out);
    } else {
        updatenet_fallback<<<grid, 256, 0, stream>>>(x, w1, w2, out);
    }
}

// Round 17
// 221.409 us; speedup vs baseline: 1.5195x; 1.5195x over previous
//
#include <hip/hip_runtime.h>

#define CIN 16
#define HH 256
#define WW 256
#define HID 128
#define KEFF 144        // 9 taps * 16 channels
#define WS_BYTES (HID * KEFF * 2 + CIN * HID * 2)   // 36864 + 4096 = 40960

typedef short short8b __attribute__((ext_vector_type(8)));
typedef float f32x4 __attribute__((ext_vector_type(4)));

// fp32 -> bf16 round-to-nearest-even (finite inputs)
__device__ __forceinline__ unsigned short f2bf(float f) {
    union { float f; unsigned int u; } v; v.f = f;
    unsigned int u = v.u;
    return (unsigned short)((u + 0x7fffu + ((u >> 16) & 1u)) >> 16);
}

// Pre-kernel: Weff[o][tap][c] = W1[o][c]*d(tap==4) + W1[o][16+c]*Sx + W1[o][32+c]*Sy ; then w2 bf16.
__global__ __launch_bounds__(256) void build_weff(
    const float* __restrict__ w1, const float* __restrict__ w2,
    unsigned short* __restrict__ ws)
{
    const float SX[9] = {-1.f, 0.f, 1.f, -2.f, 0.f, 2.f, -1.f, 0.f, 1.f};
    const float SY[9] = {-1.f, -2.f, -1.f, 0.f, 0.f, 0.f, 1.f, 2.f, 1.f};
    const int idx = blockIdx.x * 256 + threadIdx.x;
    if (idx < HID * KEFF) {
        const int o = idx / KEFF, r = idx % KEFF;
        const int tap = r >> 4, c = r & 15;
        float v = w1[o * 48 + 16 + c] * SX[tap] + w1[o * 48 + 32 + c] * SY[tap];
        if (tap == 4) v += w1[o * 48 + c];
        ws[idx] = f2bf(v);
    } else if (idx < HID * KEFF + CIN * HID) {
        ws[idx] = f2bf(w2[idx - HID * KEFF]);
    }
}

// v13 LDS carve (bytes):
//   xl   : [0, 19584)        [34][18][16] bf16 channel-last, 32 B/pixel
//   hbuf : [19584, 52352)    [2 p][4 rows][16 px][256 B], XOR-swizzled slabs
//   zreg : [52352, 52384)    32 B zeros
// 52.4 KB -> 3 blocks/CU
#define SMD_XL  0
#define SMD_HB  19584
#define SMD_ZR  52352
#define SMD_TOT 52384

// v12's S=4 A-amortization (A-traffic /4) with m97-SHAPED LIVENESS: acc[4][4]
// is fully drained (h written for all 4 rows) BEFORE the first barrier — no
// accumulator lives across any __syncthreads. v12 violated this (acc[..][3]
// survived 3 barriers) and the allocator spilled it to scratch: FETCH 544 MB,
// 336 us. m97's GEMM (same 64-acc footprint, barrier-free acc liveness) holds
// 64 AGPRs with zero spill. Barriers: 2/sup (A: h visible; B: slab reuse).
// Layer-2: wave q handles rows {q, q+2} — both waves busy, none idle.
__global__ __launch_bounds__(256) void updatenet_v13(
    const float* __restrict__ x,             // [B,16,256,256]
    const unsigned short* __restrict__ ws,   // bf16 weff[128][144] + w2[16][128]
    float* __restrict__ out)                 // [B,16,256,256]
{
    __shared__ __align__(16) unsigned char smem[SMD_TOT];
    unsigned short* xl   = (unsigned short*)(smem + SMD_XL);
    unsigned short* zreg = (unsigned short*)(smem + SMD_ZR);

    const int b  = blockIdx.z;
    const int i0 = blockIdx.y * 32;
    const int j0 = blockIdx.x * 16;
    const int t  = threadIdx.x;     // 0..255

    // ---- stage x tile 34x18 (channel-last bf16, zero-pad OOB) ----
    {
        const size_t cs = (size_t)HH * WW;
        for (int pidx = t; pidx < 34 * 18; pidx += 256) {
            const int ri = pidx / 18, rj = pidx % 18;
            const int ii = i0 + ri - 1, jj = j0 + rj - 1;
            const bool ok = (ii >= 0) & (ii < HH) & (jj >= 0) & (jj < WW);
            const float* xp = x + ((size_t)b * CIN * HH + ii) * WW + jj;
            short8b s0, s1;
            #pragma unroll
            for (int c = 0; c < 8; ++c) {
                s0[c] = ok ? (short)f2bf(xp[c * cs]) : (short)0;
                s1[c] = ok ? (short)f2bf(xp[(c + 8) * cs]) : (short)0;
            }
            *(short8b*)(xl + pidx * 16)     = s0;
            *(short8b*)(xl + pidx * 16 + 8) = s1;
        }
        if (t < 2) *(short8b*)(zreg + t * 8) = (short8b)0;
    }

    const int wv   = t >> 6;        // 0..3
    const int lane = t & 63;
    const int p    = wv >> 1;       // pixel half: rows 16p..16p+15
    const int q    = wv & 1;        // o half: o in [64q, 64q+64)
    const int g    = lane >> 4;     // k-group 0..3
    const int nn   = lane & 15;     // MFMA row/col-in-tile
    const int gh   = g >> 1, gl = g & 1;

    // per-lane tap byte-offsets into xl: tap = 2ks+gh, (di,dj) = (tap/3, tap%3)
    int off[5];
    #pragma unroll
    for (int ks = 0; ks < 5; ++ks) {
        int tap = 2 * ks + gh;
        if (tap > 8) tap = 8;       // ks=4,gh=1 -> B redirected to zreg
        off[ks] = ((tap / 3) * 18 + (tap % 3)) * 32 + gl * 16;
    }

    unsigned char* hb_p = smem + SMD_HB + p * 16384;   // 4 slabs x 4096 B
    const int xmask = (nn & 7) << 4;                    // per-slab XOR swizzle

    __syncthreads();

    // ---- 4 super-iterations of 4 rows each ----
    for (int sup = 0; sup < 4; ++sup) {
        const int r0 = 16 * p + 4 * sup;

        // layer-1, k-outer over 4 rows: acc[mt][s] — NO barrier while live
        f32x4 acc[4][4];
        #pragma unroll
        for (int mt = 0; mt < 4; ++mt)
            #pragma unroll
            for (int s = 0; s < 4; ++s) acc[mt][s] = (f32x4)0.f;

        #pragma unroll
        for (int ks = 0; ks < 5; ++ks) {
            short8b Bf[4];
            #pragma unroll
            for (int s = 0; s < 4; ++s) {
                const unsigned char* bp = (ks == 4 && gh)
                    ? (const unsigned char*)(zreg + gl * 8)
                    : (const unsigned char*)xl + ((r0 + s) * 18 + nn) * 32 + off[ks];
                Bf[s] = *(const short8b*)bp;
            }
            // ks<4: k = 32ks+8g. ks=4: k = 128+8*gl (payload for g=0,1; g>=2
            // reads in-row data x zero-B — never leaves its 144-elem row).
            const int ak = (ks == 4) ? (128 + 8 * gl) : (32 * ks + 8 * g);
            #pragma unroll
            for (int mt = 0; mt < 4; ++mt) {
                const short8b Af = *(const short8b*)(ws + (size_t)(64 * q + 16 * mt + nn) * KEFF + ak);
                #pragma unroll
                for (int s = 0; s < 4; ++s)
                    acc[mt][s] = __builtin_amdgcn_mfma_f32_16x16x32_bf16(Af, Bf[s], acc[mt][s], 0, 0, 0);
            }
        }

        // drain acc -> h slabs (all 4 rows) BEFORE any barrier
        #pragma unroll
        for (int s = 0; s < 4; ++s) {
            unsigned char* slab = hb_p + s * 4096;
            #pragma unroll
            for (int mt = 0; mt < 4; ++mt) {
                const unsigned int lo = (unsigned int)f2bf(fmaxf(acc[mt][s][0], 0.f))
                                      | ((unsigned int)f2bf(fmaxf(acc[mt][s][1], 0.f)) << 16);
                const unsigned int hi = (unsigned int)f2bf(fmaxf(acc[mt][s][2], 0.f))
                                      | ((unsigned int)f2bf(fmaxf(acc[mt][s][3], 0.f)) << 16);
                uint2 u; u.x = lo; u.y = hi;
                const int wb = (nn << 8) + ((64 * q + 16 * mt + 4 * g) << 1);
                *(uint2*)(slab + (wb ^ xmask)) = u;
            }
        }

        __syncthreads();   // A: all 4 rows' h visible to both q-waves of this p

        // layer-2 (full K=128): wave q handles rows q and q+2
        #pragma unroll
        for (int rr = 0; rr < 2; ++rr) {
            const int srow = q + 2 * rr;
            const unsigned char* slab = hb_p + srow * 4096;
            f32x4 a2 = (f32x4)0.f;
            #pragma unroll
            for (int ks2 = 0; ks2 < 4; ++ks2) {
                const short8b aw2 = *(const short8b*)(ws + HID * KEFF + nn * HID + 32 * ks2 + 8 * g);
                const int rb = (nn << 8) + ((32 * ks2 + 8 * g) << 1);
                const short8b bh = *(const short8b*)(slab + (rb ^ xmask));
                a2 = __builtin_amdgcn_mfma_f32_16x16x32_bf16(aw2, bh, a2, 0, 0, 0);
            }
            const int oi = i0 + r0 + srow, oj = j0 + nn;
            float* op = out + ((size_t)(b * CIN + 4 * g) * HH + oi) * WW + oj;
            #pragma unroll
            for (int r = 0; r < 4; ++r)
                op[(size_t)r * HH * WW] = a2[r];
        }

        __syncthreads();   // B: slab reads done before next sup overwrites
    }
}

// ---------- fallback (no usable ws): proven round-4 kernel ----------
#define SM_WEFF  0
#define SM_GUARD 36864
#define SM_W2B   36880
#define SM_XL    41232
#define SM_ZREG  60816
#define SM_HALL  60848
#define SM_TOTAL 78256

__global__ __launch_bounds__(256, 2) void updatenet_fallback(
    const float* __restrict__ x, const float* __restrict__ w1f,
    const float* __restrict__ w2f, float* __restrict__ out)
{
    __shared__ __align__(16) unsigned char smem[SM_TOTAL];
    unsigned short* weff = (unsigned short*)(smem + SM_WEFF);
    unsigned short* w2b  = (unsigned short*)(smem + SM_W2B);
    unsigned short* xl   = (unsigned short*)(smem + SM_XL);
    unsigned short* zreg = (unsigned short*)(smem + SM_ZREG);

    const int b  = blockIdx.z;
    const int i0 = blockIdx.y * 32;
    const int j0 = blockIdx.x * 16;
    const int t  = threadIdx.x;

    for (int idx = t; idx < HID * KEFF; idx += 256) {
        const float SX[9] = {-1.f, 0.f, 1.f, -2.f, 0.f, 2.f, -1.f, 0.f, 1.f};
        const float SY[9] = {-1.f, -2.f, -1.f, 0.f, 0.f, 0.f, 1.f, 2.f, 1.f};
        const int o = idx / KEFF, r = idx % KEFF;
        const int tap = r >> 4, cc = r & 15;
        float v = w1f[o * 48 + 16 + cc] * SX[tap] + w1f[o * 48 + 32 + cc] * SY[tap];
        if (tap == 4) v += w1f[o * 48 + cc];
        weff[idx] = f2bf(v);
    }
    for (int idx = t; idx < CIN * HID; idx += 256)
        w2b[(idx >> 7) * 136 + (idx & 127)] = f2bf(w2f[idx]);

    {
        const size_t cs = (size_t)HH * WW;
        for (int pp = t; pp < 34 * 18; pp += 256) {
            const int ri = pp / 18, rj = pp % 18;
            const int ii = i0 + ri - 1, jj = j0 + rj - 1;
            const bool ok = (ii >= 0) & (ii < HH) & (jj >= 0) & (jj < WW);
            const float* xp = x + ((size_t)b * CIN * HH + ii) * WW + jj;
            short8b s0, s1;
            #pragma unroll
            for (int c = 0; c < 8; ++c) {
                s0[c] = ok ? (short)f2bf(xp[c * cs]) : (short)0;
                s1[c] = ok ? (short)f2bf(xp[(c + 8) * cs]) : (short)0;
            }
            *(short8b*)(xl + pp * 16)     = s0;
            *(short8b*)(xl + pp * 16 + 8) = s1;
        }
        if (t < 2) *(short8b*)(zreg + t * 8) = (short8b)0;
        if (t == 2) *(short8b*)(smem + SM_GUARD) = (short8b)0;
    }
    __syncthreads();

    const int w = t >> 6, lane = t & 63;
    const int g = lane >> 4, nn = lane & 15;
    const int gh = g >> 1, gl = g & 1;

    short8b aW1[8][5];
    #pragma unroll
    for (int m = 0; m < 8; ++m)
        #pragma unroll
        for (int ks = 0; ks < 5; ++ks) {
            const int ak = (ks == 4) ? (128 + 8 * gl) : (32 * ks + 8 * g);
            aW1[m][ks] = *(const short8b*)(weff + (16 * m + nn) * KEFF + ak);
        }

    int off[5];
    #pragma unroll
    for (int ks = 0; ks < 5; ++ks) {
        int tap = 2 * ks + gh;
        if (tap > 8) tap = 8;
        off[ks] = ((tap / 3) * 18 + (tap % 3)) * 32 + gl * 16;
    }

    unsigned short* hb = (unsigned short*)(smem + SM_HALL) + w * (16 * 136);

    for (int nt = 0; nt < 8; ++nt) {
        const int i = 8 * w + nt;
        const unsigned char* xbase = (const unsigned char*)xl + (i * 18 + nn) * 32;
        f32x4 acc[8];
        #pragma unroll
        for (int m = 0; m < 8; ++m) acc[m] = (f32x4)0.f;
        #pragma unroll
        for (int ks = 0; ks < 5; ++ks) {
            const unsigned char* bp = (ks == 4 && gh) ? (const unsigned char*)(zreg + gl * 8)
                                                      : xbase + off[ks];
            const short8b bfrag = *(const short8b*)bp;
            #pragma unroll
            for (int m = 0; m < 8; ++m)
                acc[m] = __builtin_amdgcn_mfma_f32_16x16x32_bf16(aW1[m][ks], bfrag, acc[m], 0, 0, 0);
        }
        #pragma unroll
        for (int m = 0; m < 8; ++m) {
            const unsigned int lo = (unsigned int)f2bf(fmaxf(acc[m][0], 0.f))
                                  | ((unsigned int)f2bf(fmaxf(acc[m][1], 0.f)) << 16);
            const unsigned int hi = (unsigned int)f2bf(fmaxf(acc[m][2], 0.f))
                                  | ((unsigned int)f2bf(fmaxf(acc[m][3], 0.f)) << 16);
            uint2 u; u.x = lo; u.y = hi;
            *(uint2*)(hb + nn * 136 + 16 * m + 4 * g) = u;
        }
        asm volatile("s_waitcnt lgkmcnt(0)" ::: "memory");
        f32x4 a2 = (f32x4)0.f;
        #pragma unroll
        for (int ks = 0; ks < 4; ++ks) {
            const short8b aw2 = *(const short8b*)(w2b + nn * 136 + 32 * ks + 8 * g);
            const short8b bh  = *(const short8b*)(hb + nn * 136 + 32 * ks + 8 * g);
            a2 = __builtin_amdgcn_mfma_f32_16x16x32_bf16(aw2, bh, a2, 0, 0, 0);
        }
        const int oi = i0 + i, oj = j0 + nn;
        float* op = out + ((size_t)(b * CIN + 4 * g) * HH + oi) * WW + oj;
        #pragma unroll
        for (int r = 0; r < 4; ++r)
            op[(size_t)r * HH * WW] = a2[r];
    }
}

extern "C" void kernel_launch(void* const* d_in, const int* in_sizes, int n_in,
                              void* d_out, int out_size, void* d_ws, size_t ws_size,
                              hipStream_t stream) {
    const float* x  = (const float*)d_in[0];
    const float* w1 = (const float*)d_in[1];
    const float* w2 = (const float*)d_in[2];
    float* out = (float*)d_out;

    const int Bn = in_sizes[0] / (CIN * HH * WW);   // 32
    dim3 grid(WW / 16, HH / 32, Bn);                // 16 x 8 x 32 = 4096 blocks

    if (ws_size >= (size_t)WS_BYTES) {
        unsigned short* ws = (unsigned short*)d_ws;
        build_weff<<<(HID * KEFF + CIN * HID + 255) / 256, 256, 0, stream>>>(w1, w2, ws);
        updatenet_v13<<<grid, 256, 0, stream>>>(x, ws, out);
    } else {
        updatenet_fallback<<<grid, 256, 0, stream>>>(x, w1, w2, out);
    }
}

// Round 18
// 139.918 us; speedup vs baseline: 2.4046x; 1.5824x over previous
//
#include <hip/hip_runtime.h>

#define CIN 16
#define HH 256
#define WW 256
#define HID 128
#define KEFF 144        // 9 taps * 16 channels
#define WS_W_BYTES (HID * KEFF * 2 + CIN * HID * 2)   // 40960
#define X2_OFF_SHORTS 20480                            // 40960 B / 2

typedef short short8b __attribute__((ext_vector_type(8)));
typedef float f32x4 __attribute__((ext_vector_type(4)));

__device__ __forceinline__ unsigned short f2bf(float f) {
    union { float f; unsigned int u; } v; v.f = f;
    unsigned int u = v.u;
    return (unsigned short)((u + 0x7fffu + ((u >> 16) & 1u)) >> 16);
}

// Pre-kernel 1: Weff[o][tap][c] + w2 bf16 into ws[0:40960)
__global__ __launch_bounds__(256) void build_weff(
    const float* __restrict__ w1, const float* __restrict__ w2,
    unsigned short* __restrict__ ws)
{
    const float SX[9] = {-1.f, 0.f, 1.f, -2.f, 0.f, 2.f, -1.f, 0.f, 1.f};
    const float SY[9] = {-1.f, -2.f, -1.f, 0.f, 0.f, 0.f, 1.f, 2.f, 1.f};
    const int idx = blockIdx.x * 256 + threadIdx.x;
    if (idx < HID * KEFF) {
        const int o = idx / KEFF, r = idx % KEFF;
        const int tap = r >> 4, c = r & 15;
        float v = w1[o * 48 + 16 + c] * SX[tap] + w1[o * 48 + 32 + c] * SY[tap];
        if (tap == 4) v += w1[o * 48 + c];
        ws[idx] = f2bf(v);
    } else if (idx < HID * KEFF + CIN * HID) {
        ws[idx] = f2bf(w2[idx - HID * KEFF]);
    }
}

// Pre-kernel 2: NCHW f32 -> NHWC bf16 (x2 at ws+X2_OFF_SHORTS).
// Block = one (b,ii) row: 16 coalesced 256-lane channel reads, 32B/px writes.
__global__ __launch_bounds__(256) void nchw_to_nhwc(
    const float* __restrict__ x, unsigned short* __restrict__ x2)
{
    const int bi = blockIdx.x;          // b*256 + ii
    const int b = bi >> 8, ii = bi & 255;
    const int jj = threadIdx.x;
    short8b lo, hi;
    #pragma unroll
    for (int c = 0; c < 8; ++c) {
        lo[c] = (short)f2bf(x[((size_t)(b * CIN + c) * HH + ii) * WW + jj]);
        hi[c] = (short)f2bf(x[((size_t)(b * CIN + c + 8) * HH + ii) * WW + jj]);
    }
    unsigned short* dst = x2 + ((size_t)(b * HH + ii) * WW + jj) * 16;
    *(short8b*)dst       = lo;
    *(short8b*)(dst + 8) = hi;
}

// LDS carve (bytes) — shared by v14 and v8mid:
//   xl   : [0, 19584)        [34][18][16] bf16 channel-last, 32 B/pixel
//   hbuf : [19584, 35968)    [2 p][2 phase][16 px][256 B], XOR-swizzled
//   zreg : [35968, 36000)    32 B zeros
#define SM6_XL  0
#define SM6_HB  19584
#define SM6_ZR  35968
#define SM6_TOT 36000

// v14 = v8's proven body (181us wall, best measured) with staging swapped from
// 38 scalar NCHW-f32 gathers + 32 f2bf per thread to 4.8 coalesced 16B copies
// of pre-transposed NHWC bf16. Theory (r17): the flat ~176-180us floor across
// v5/v7/v8/v11 (occupancy x1.4 and A-traffic /4 both no-ops) is staging
// issue/latency + VALU, not exchange bandwidth.
__global__ __launch_bounds__(256, 2) void updatenet_v14(
    const unsigned short* __restrict__ ws,   // weff + w2 bf16; x2 at +20480
    float* __restrict__ out)
{
    __shared__ __align__(16) unsigned char smem[SM6_TOT];
    unsigned short* xl   = (unsigned short*)(smem + SM6_XL);
    unsigned short* zreg = (unsigned short*)(smem + SM6_ZR);

    const int b  = blockIdx.z;
    const int i0 = blockIdx.y * 32;
    const int j0 = blockIdx.x * 16;
    const int t  = threadIdx.x;

    // ---- stage x tile from NHWC bf16: 1224 coalesced short8b copies ----
    {
        const unsigned short* x2 = ws + X2_OFF_SHORTS;
        for (int idx = t; idx < 34 * 18 * 2; idx += 256) {
            const int ri = idx / 36, rem = idx % 36;
            const int rj = rem >> 1, half = rem & 1;
            const int ii = i0 + ri - 1, jj = j0 + rj - 1;
            short8b v = (short8b)0;
            if (ii >= 0 && ii < HH && jj >= 0 && jj < WW)
                v = *(const short8b*)(x2 + ((size_t)(b * HH + ii) * WW + jj) * 16 + half * 8);
            *(short8b*)(xl + (ri * 18 + rj) * 16 + half * 8) = v;
        }
        if (t < 2) *(short8b*)(zreg + t * 8) = (short8b)0;
    }

    const int wv   = t >> 6;
    const int lane = t & 63;
    const int p    = wv >> 1;       // pixel half: rows 16p..16p+15
    const int q    = wv & 1;        // o half
    const int g    = lane >> 4;
    const int nn   = lane & 15;
    const int gh   = g >> 1, gl = g & 1;

    // A1 frags (compiler will remat per-row from L2-hot ws — measured neutral)
    short8b aW1[4][5];
    #pragma unroll
    for (int mt = 0; mt < 4; ++mt)
        #pragma unroll
        for (int ks = 0; ks < 5; ++ks) {
            const int ak = (ks == 4) ? (128 + 8 * gl) : (32 * ks + 8 * g);
            aW1[mt][ks] = *(const short8b*)(ws + (size_t)(64 * q + 16 * mt + nn) * KEFF + ak);
        }
    short8b aW2[4];
    #pragma unroll
    for (int ks = 0; ks < 4; ++ks)
        aW2[ks] = *(const short8b*)(ws + HID * KEFF + nn * HID + 32 * ks + 8 * g);

    int off[5];
    #pragma unroll
    for (int ks = 0; ks < 5; ++ks) {
        int tap = 2 * ks + gh;
        if (tap > 8) tap = 8;
        off[ks] = ((tap / 3) * 18 + (tap % 3)) * 32 + gl * 16;
    }

    unsigned char* hb_pair = smem + SM6_HB + p * 8192;
    const int xmask = (nn & 7) << 4;

    __syncthreads();

    for (int s = 0; s < 16; ++s) {
        const int row = 16 * p + s;
        const unsigned char* xbase = (const unsigned char*)xl + (row * 18 + nn) * 32;

        f32x4 acc[4];
        #pragma unroll
        for (int mt = 0; mt < 4; ++mt) acc[mt] = (f32x4)0.f;

        #pragma unroll
        for (int ks = 0; ks < 5; ++ks) {
            const unsigned char* bp = (ks == 4 && gh) ? (const unsigned char*)(zreg + gl * 8)
                                                      : xbase + off[ks];
            const short8b bfrag = *(const short8b*)bp;
            #pragma unroll
            for (int mt = 0; mt < 4; ++mt)
                acc[mt] = __builtin_amdgcn_mfma_f32_16x16x32_bf16(aW1[mt][ks], bfrag, acc[mt], 0, 0, 0);
        }

        unsigned char* hph = hb_pair + (s & 1) * 4096;
        #pragma unroll
        for (int mt = 0; mt < 4; ++mt) {
            const unsigned int lo = (unsigned int)f2bf(fmaxf(acc[mt][0], 0.f))
                                  | ((unsigned int)f2bf(fmaxf(acc[mt][1], 0.f)) << 16);
            const unsigned int hi = (unsigned int)f2bf(fmaxf(acc[mt][2], 0.f))
                                  | ((unsigned int)f2bf(fmaxf(acc[mt][3], 0.f)) << 16);
            uint2 u; u.x = lo; u.y = hi;
            const int wb = (nn << 8) + ((64 * q + 16 * mt + 4 * g) << 1);
            *(uint2*)(hph + (wb ^ xmask)) = u;
        }

        __syncthreads();

        if (q == (s & 1)) {
            f32x4 a2 = (f32x4)0.f;
            #pragma unroll
            for (int ks2 = 0; ks2 < 4; ++ks2) {
                const int rb = (nn << 8) + ((32 * ks2 + 8 * g) << 1);
                const short8b bh = *(const short8b*)(hph + (rb ^ xmask));
                a2 = __builtin_amdgcn_mfma_f32_16x16x32_bf16(aW2[ks2], bh, a2, 0, 0, 0);
            }
            const int oi = i0 + row, oj = j0 + nn;
            float* op = out + ((size_t)(b * CIN + 4 * g) * HH + oi) * WW + oj;
            #pragma unroll
            for (int r = 0; r < 4; ++r)
                op[(size_t)r * HH * WW] = a2[r];
        }
    }
}

// ---------- middle tier: proven v8 (x from NCHW f32, scalar staging) ----------
__global__ __launch_bounds__(256, 2) void updatenet_v8m(
    const float* __restrict__ x,
    const unsigned short* __restrict__ ws,
    float* __restrict__ out)
{
    __shared__ __align__(16) unsigned char smem[SM6_TOT];
    unsigned short* xl   = (unsigned short*)(smem + SM6_XL);
    unsigned short* zreg = (unsigned short*)(smem + SM6_ZR);

    const int b  = blockIdx.z;
    const int i0 = blockIdx.y * 32;
    const int j0 = blockIdx.x * 16;
    const int t  = threadIdx.x;

    {
        const size_t cs = (size_t)HH * WW;
        for (int pidx = t; pidx < 34 * 18; pidx += 256) {
            const int ri = pidx / 18, rj = pidx % 18;
            const int ii = i0 + ri - 1, jj = j0 + rj - 1;
            const bool ok = (ii >= 0) & (ii < HH) & (jj >= 0) & (jj < WW);
            const float* xp = x + ((size_t)b * CIN * HH + ii) * WW + jj;
            short8b s0, s1;
            #pragma unroll
            for (int c = 0; c < 8; ++c) {
                s0[c] = ok ? (short)f2bf(xp[c * cs]) : (short)0;
                s1[c] = ok ? (short)f2bf(xp[(c + 8) * cs]) : (short)0;
            }
            *(short8b*)(xl + pidx * 16)     = s0;
            *(short8b*)(xl + pidx * 16 + 8) = s1;
        }
        if (t < 2) *(short8b*)(zreg + t * 8) = (short8b)0;
    }

    const int wv   = t >> 6;
    const int lane = t & 63;
    const int p    = wv >> 1;
    const int q    = wv & 1;
    const int g    = lane >> 4;
    const int nn   = lane & 15;
    const int gh   = g >> 1, gl = g & 1;

    short8b aW1[4][5];
    #pragma unroll
    for (int mt = 0; mt < 4; ++mt)
        #pragma unroll
        for (int ks = 0; ks < 5; ++ks) {
            const int ak = (ks == 4) ? (128 + 8 * gl) : (32 * ks + 8 * g);
            aW1[mt][ks] = *(const short8b*)(ws + (size_t)(64 * q + 16 * mt + nn) * KEFF + ak);
        }
    short8b aW2[4];
    #pragma unroll
    for (int ks = 0; ks < 4; ++ks)
        aW2[ks] = *(const short8b*)(ws + HID * KEFF + nn * HID + 32 * ks + 8 * g);

    int off[5];
    #pragma unroll
    for (int ks = 0; ks < 5; ++ks) {
        int tap = 2 * ks + gh;
        if (tap > 8) tap = 8;
        off[ks] = ((tap / 3) * 18 + (tap % 3)) * 32 + gl * 16;
    }

    unsigned char* hb_pair = smem + SM6_HB + p * 8192;
    const int xmask = (nn & 7) << 4;

    __syncthreads();

    for (int s = 0; s < 16; ++s) {
        const int row = 16 * p + s;
        const unsigned char* xbase = (const unsigned char*)xl + (row * 18 + nn) * 32;

        f32x4 acc[4];
        #pragma unroll
        for (int mt = 0; mt < 4; ++mt) acc[mt] = (f32x4)0.f;

        #pragma unroll
        for (int ks = 0; ks < 5; ++ks) {
            const unsigned char* bp = (ks == 4 && gh) ? (const unsigned char*)(zreg + gl * 8)
                                                      : xbase + off[ks];
            const short8b bfrag = *(const short8b*)bp;
            #pragma unroll
            for (int mt = 0; mt < 4; ++mt)
                acc[mt] = __builtin_amdgcn_mfma_f32_16x16x32_bf16(aW1[mt][ks], bfrag, acc[mt], 0, 0, 0);
        }

        unsigned char* hph = hb_pair + (s & 1) * 4096;
        #pragma unroll
        for (int mt = 0; mt < 4; ++mt) {
            const unsigned int lo = (unsigned int)f2bf(fmaxf(acc[mt][0], 0.f))
                                  | ((unsigned int)f2bf(fmaxf(acc[mt][1], 0.f)) << 16);
            const unsigned int hi = (unsigned int)f2bf(fmaxf(acc[mt][2], 0.f))
                                  | ((unsigned int)f2bf(fmaxf(acc[mt][3], 0.f)) << 16);
            uint2 u; u.x = lo; u.y = hi;
            const int wb = (nn << 8) + ((64 * q + 16 * mt + 4 * g) << 1);
            *(uint2*)(hph + (wb ^ xmask)) = u;
        }

        __syncthreads();

        if (q == (s & 1)) {
            f32x4 a2 = (f32x4)0.f;
            #pragma unroll
            for (int ks2 = 0; ks2 < 4; ++ks2) {
                const int rb = (nn << 8) + ((32 * ks2 + 8 * g) << 1);
                const short8b bh = *(const short8b*)(hph + (rb ^ xmask));
                a2 = __builtin_amdgcn_mfma_f32_16x16x32_bf16(aW2[ks2], bh, a2, 0, 0, 0);
            }
            const int oi = i0 + row, oj = j0 + nn;
            float* op = out + ((size_t)(b * CIN + 4 * g) * HH + oi) * WW + oj;
            #pragma unroll
            for (int r = 0; r < 4; ++r)
                op[(size_t)r * HH * WW] = a2[r];
        }
    }
}

// ---------- last tier: no-ws fallback (round-4 proven) ----------
#define SM_WEFF  0
#define SM_GUARD 36864
#define SM_W2B   36880
#define SM_XL    41232
#define SM_ZREG  60816
#define SM_HALL  60848
#define SM_TOTAL 78256

__global__ __launch_bounds__(256, 2) void updatenet_fallback(
    const float* __restrict__ x, const float* __restrict__ w1f,
    const float* __restrict__ w2f, float* __restrict__ out)
{
    __shared__ __align__(16) unsigned char smem[SM_TOTAL];
    unsigned short* weff = (unsigned short*)(smem + SM_WEFF);
    unsigned short* w2b  = (unsigned short*)(smem + SM_W2B);
    unsigned short* xl   = (unsigned short*)(smem + SM_XL);
    unsigned short* zreg = (unsigned short*)(smem + SM_ZREG);

    const int b  = blockIdx.z;
    const int i0 = blockIdx.y * 32;
    const int j0 = blockIdx.x * 16;
    const int t  = threadIdx.x;

    for (int idx = t; idx < HID * KEFF; idx += 256) {
        const float SX[9] = {-1.f, 0.f, 1.f, -2.f, 0.f, 2.f, -1.f, 0.f, 1.f};
        const float SY[9] = {-1.f, -2.f, -1.f, 0.f, 0.f, 0.f, 1.f, 2.f, 1.f};
        const int o = idx / KEFF, r = idx % KEFF;
        const int tap = r >> 4, cc = r & 15;
        float v = w1f[o * 48 + 16 + cc] * SX[tap] + w1f[o * 48 + 32 + cc] * SY[tap];
        if (tap == 4) v += w1f[o * 48 + cc];
        weff[idx] = f2bf(v);
    }
    for (int idx = t; idx < CIN * HID; idx += 256)
        w2b[(idx >> 7) * 136 + (idx & 127)] = f2bf(w2f[idx]);

    {
        const size_t cs = (size_t)HH * WW;
        for (int pp = t; pp < 34 * 18; pp += 256) {
            const int ri = pp / 18, rj = pp % 18;
            const int ii = i0 + ri - 1, jj = j0 + rj - 1;
            const bool ok = (ii >= 0) & (ii < HH) & (jj >= 0) & (jj < WW);
            const float* xp = x + ((size_t)b * CIN * HH + ii) * WW + jj;
            short8b s0, s1;
            #pragma unroll
            for (int c = 0; c < 8; ++c) {
                s0[c] = ok ? (short)f2bf(xp[c * cs]) : (short)0;
                s1[c] = ok ? (short)f2bf(xp[(c + 8) * cs]) : (short)0;
            }
            *(short8b*)(xl + pp * 16)     = s0;
            *(short8b*)(xl + pp * 16 + 8) = s1;
        }
        if (t < 2) *(short8b*)(zreg + t * 8) = (short8b)0;
        if (t == 2) *(short8b*)(smem + SM_GUARD) = (short8b)0;
    }
    __syncthreads();

    const int w = t >> 6, lane = t & 63;
    const int g = lane >> 4, nn = lane & 15;
    const int gh = g >> 1, gl = g & 1;

    short8b aW1[8][5];
    #pragma unroll
    for (int m = 0; m < 8; ++m)
        #pragma unroll
        for (int ks = 0; ks < 5; ++ks) {
            const int ak = (ks == 4) ? (128 + 8 * gl) : (32 * ks + 8 * g);
            aW1[m][ks] = *(const short8b*)(weff + (16 * m + nn) * KEFF + ak);
        }

    int off[5];
    #pragma unroll
    for (int ks = 0; ks < 5; ++ks) {
        int tap = 2 * ks + gh;
        if (tap > 8) tap = 8;
        off[ks] = ((tap / 3) * 18 + (tap % 3)) * 32 + gl * 16;
    }

    unsigned short* hb = (unsigned short*)(smem + SM_HALL) + w * (16 * 136);

    for (int nt = 0; nt < 8; ++nt) {
        const int i = 8 * w + nt;
        const unsigned char* xbase = (const unsigned char*)xl + (i * 18 + nn) * 32;
        f32x4 acc[8];
        #pragma unroll
        for (int m = 0; m < 8; ++m) acc[m] = (f32x4)0.f;
        #pragma unroll
        for (int ks = 0; ks < 5; ++ks) {
            const unsigned char* bp = (ks == 4 && gh) ? (const unsigned char*)(zreg + gl * 8)
                                                      : xbase + off[ks];
            const short8b bfrag = *(const short8b*)bp;
            #pragma unroll
            for (int m = 0; m < 8; ++m)
                acc[m] = __builtin_amdgcn_mfma_f32_16x16x32_bf16(aW1[m][ks], bfrag, acc[m], 0, 0, 0);
        }
        #pragma unroll
        for (int m = 0; m < 8; ++m) {
            const unsigned int lo = (unsigned int)f2bf(fmaxf(acc[m][0], 0.f))
                                  | ((unsigned int)f2bf(fmaxf(acc[m][1], 0.f)) << 16);
            const unsigned int hi = (unsigned int)f2bf(fmaxf(acc[m][2], 0.f))
                                  | ((unsigned int)f2bf(fmaxf(acc[m][3], 0.f)) << 16);
            uint2 u; u.x = lo; u.y = hi;
            *(uint2*)(hb + nn * 136 + 16 * m + 4 * g) = u;
        }
        asm volatile("s_waitcnt lgkmcnt(0)" ::: "memory");
        f32x4 a2 = (f32x4)0.f;
        #pragma unroll
        for (int ks = 0; ks < 4; ++ks) {
            const short8b aw2 = *(const short8b*)(w2b + nn * 136 + 32 * ks + 8 * g);
            const short8b bh  = *(const short8b*)(hb + nn * 136 + 32 * ks + 8 * g);
            a2 = __builtin_amdgcn_mfma_f32_16x16x32_bf16(aw2, bh, a2, 0, 0, 0);
        }
        const int oi = i0 + i, oj = j0 + nn;
        float* op = out + ((size_t)(b * CIN + 4 * g) * HH + oi) * WW + oj;
        #pragma unroll
        for (int r = 0; r < 4; ++r)
            op[(size_t)r * HH * WW] = a2[r];
    }
}

extern "C" void kernel_launch(void* const* d_in, const int* in_sizes, int n_in,
                              void* d_out, int out_size, void* d_ws, size_t ws_size,
                              hipStream_t stream) {
    const float* x  = (const float*)d_in[0];
    const float* w1 = (const float*)d_in[1];
    const float* w2 = (const float*)d_in[2];
    float* out = (float*)d_out;

    const int Bn = in_sizes[0] / (CIN * HH * WW);   // 32
    dim3 grid(WW / 16, HH / 32, Bn);                // 4096 blocks

    const size_t x2_bytes = (size_t)Bn * CIN * HH * WW * 2;   // 67.1 MB

    if (ws_size >= (size_t)WS_W_BYTES + x2_bytes) {
        unsigned short* ws = (unsigned short*)d_ws;
        build_weff<<<(HID * KEFF + CIN * HID + 255) / 256, 256, 0, stream>>>(w1, w2, ws);
        nchw_to_nhwc<<<Bn * HH, 256, 0, stream>>>(x, ws + X2_OFF_SHORTS);
        updatenet_v14<<<grid, 256, 0, stream>>>(ws, out);
    } else if (ws_size >= (size_t)WS_W_BYTES) {
        unsigned short* ws = (unsigned short*)d_ws;
        build_weff<<<(HID * KEFF + CIN * HID + 255) / 256, 256, 0, stream>>>(w1, w2, ws);
        updatenet_v8m<<<grid, 256, 0, stream>>>(x, ws, out);
    } else {
        updatenet_fallback<<<grid, 256, 0, stream>>>(x, w1, w2, out);
    }
}

// Round 19
// 126.154 us; speedup vs baseline: 2.6669x; 1.1091x over previous
//
#include <hip/hip_runtime.h>

#define CIN 16
#define HH 256
#define WW 256
#define HID 128
#define KEFF 144        // 9 taps * 16 channels
#define WS_W_BYTES (HID * KEFF * 2 + CIN * HID * 2)   // 40960
#define X2_OFF_SHORTS 20480                            // 40960 B / 2

typedef short short8b __attribute__((ext_vector_type(8)));
typedef float f32x4 __attribute__((ext_vector_type(4)));

__device__ __forceinline__ unsigned short f2bf(float f) {
    union { float f; unsigned int u; } v; v.f = f;
    unsigned int u = v.u;
    return (unsigned short)((u + 0x7fffu + ((u >> 16) & 1u)) >> 16);
}

// packed f32x2 -> bf16x2 (RTNE), one VALU op. Replaces ~13-op f2bf+or chains.
__device__ __forceinline__ unsigned int cvtpk_bf16(float a, float b) {
    unsigned int r;
    asm volatile("v_cvt_pk_bf16_f32 %0, %1, %2" : "=v"(r) : "v"(a), "v"(b));
    return r;   // lo = bf16(a), hi = bf16(b)
}

// Pre-kernel 1: Weff[o][tap][c] + w2 bf16 into ws[0:40960)
__global__ __launch_bounds__(256) void build_weff(
    const float* __restrict__ w1, const float* __restrict__ w2,
    unsigned short* __restrict__ ws)
{
    const float SX[9] = {-1.f, 0.f, 1.f, -2.f, 0.f, 2.f, -1.f, 0.f, 1.f};
    const float SY[9] = {-1.f, -2.f, -1.f, 0.f, 0.f, 0.f, 1.f, 2.f, 1.f};
    const int idx = blockIdx.x * 256 + threadIdx.x;
    if (idx < HID * KEFF) {
        const int o = idx / KEFF, r = idx % KEFF;
        const int tap = r >> 4, c = r & 15;
        float v = w1[o * 48 + 16 + c] * SX[tap] + w1[o * 48 + 32 + c] * SY[tap];
        if (tap == 4) v += w1[o * 48 + c];
        ws[idx] = f2bf(v);
    } else if (idx < HID * KEFF + CIN * HID) {
        ws[idx] = f2bf(w2[idx - HID * KEFF]);
    }
}

// Pre-kernel 2: NCHW f32 -> NHWC bf16 (x2 at ws+X2_OFF_SHORTS).
__global__ __launch_bounds__(256) void nchw_to_nhwc(
    const float* __restrict__ x, unsigned short* __restrict__ x2)
{
    const int bi = blockIdx.x;          // b*256 + ii
    const int b = bi >> 8, ii = bi & 255;
    const int jj = threadIdx.x;
    short8b lo, hi;
    #pragma unroll
    for (int c = 0; c < 8; ++c) {
        lo[c] = (short)f2bf(x[((size_t)(b * CIN + c) * HH + ii) * WW + jj]);
        hi[c] = (short)f2bf(x[((size_t)(b * CIN + c + 8) * HH + ii) * WW + jj]);
    }
    unsigned short* dst = x2 + ((size_t)(b * HH + ii) * WW + jj) * 16;
    *(short8b*)dst       = lo;
    *(short8b*)(dst + 8) = hi;
}

// v15 LDS carve (bytes):
//   xl   : [0, 19584)        [34][18][16] bf16 channel-last, 32 B/pixel
//   hbuf : [19584, 52352)    [2 p][2 phasebuf][2 rows][4096 B], XOR-swizzled
//   zreg : [52352, 52384)    32 B zeros
// 52384 B -> 3 blocks/CU
#define SME_XL  0
#define SME_HB  19584
#define SME_ZR  52352
#define SME_TOT 52384

// v14 (140us wall; main 113us, VALU 55% / MFMA 36%) with the two VALU/barrier
// costs attacked: (1) h-pack via v_cvt_pk_bf16_f32 (52 -> ~24 VALU ops/row);
// (2) 2-row phases: acc[4][2] drained before the single barrier per phase
// (m97-shaped liveness), 16 -> 8 barriers, 40-MFMA clusters, A-remat /2.
__global__ __launch_bounds__(256, 2) void updatenet_v15(
    const unsigned short* __restrict__ ws,   // weff + w2 bf16; x2 at +20480
    float* __restrict__ out)
{
    __shared__ __align__(16) unsigned char smem[SME_TOT];
    unsigned short* xl   = (unsigned short*)(smem + SME_XL);
    unsigned short* zreg = (unsigned short*)(smem + SME_ZR);

    const int b  = blockIdx.z;
    const int i0 = blockIdx.y * 32;
    const int j0 = blockIdx.x * 16;
    const int t  = threadIdx.x;

    // ---- stage x tile from NHWC bf16: coalesced short8b copies ----
    {
        const unsigned short* x2 = ws + X2_OFF_SHORTS;
        for (int idx = t; idx < 34 * 18 * 2; idx += 256) {
            const int ri = idx / 36, rem = idx % 36;
            const int rj = rem >> 1, half = rem & 1;
            const int ii = i0 + ri - 1, jj = j0 + rj - 1;
            short8b v = (short8b)0;
            if (ii >= 0 && ii < HH && jj >= 0 && jj < WW)
                v = *(const short8b*)(x2 + ((size_t)(b * HH + ii) * WW + jj) * 16 + half * 8);
            *(short8b*)(xl + (ri * 18 + rj) * 16 + half * 8) = v;
        }
        if (t < 2) *(short8b*)(zreg + t * 8) = (short8b)0;
    }

    const int wv   = t >> 6;
    const int lane = t & 63;
    const int p    = wv >> 1;       // pixel half: rows 16p..16p+15
    const int q    = wv & 1;        // o half
    const int g    = lane >> 4;
    const int nn   = lane & 15;
    const int gh   = g >> 1, gl = g & 1;

    short8b aW1[4][5];
    #pragma unroll
    for (int mt = 0; mt < 4; ++mt)
        #pragma unroll
        for (int ks = 0; ks < 5; ++ks) {
            const int ak = (ks == 4) ? (128 + 8 * gl) : (32 * ks + 8 * g);
            aW1[mt][ks] = *(const short8b*)(ws + (size_t)(64 * q + 16 * mt + nn) * KEFF + ak);
        }
    short8b aW2[4];
    #pragma unroll
    for (int ks = 0; ks < 4; ++ks)
        aW2[ks] = *(const short8b*)(ws + HID * KEFF + nn * HID + 32 * ks + 8 * g);

    int off[5];
    #pragma unroll
    for (int ks = 0; ks < 5; ++ks) {
        int tap = 2 * ks + gh;
        if (tap > 8) tap = 8;       // ks=4,gh=1 -> B redirected to zreg
        off[ks] = ((tap / 3) * 18 + (tap % 3)) * 32 + gl * 16;
    }

    unsigned char* hb_p = smem + SME_HB + p * 16384;   // 2 phasebufs x 8192 B
    const int xmask = (nn & 7) << 4;

    __syncthreads();

    // ---- 8 phases of 2 rows each ----
    for (int phs = 0; phs < 8; ++phs) {
        const int r0 = 16 * p + 2 * phs;

        // layer-1 k-outer over 2 rows: acc[mt][rr] — no barrier while live
        f32x4 acc[4][2];
        #pragma unroll
        for (int mt = 0; mt < 4; ++mt) {
            acc[mt][0] = (f32x4)0.f;
            acc[mt][1] = (f32x4)0.f;
        }

        #pragma unroll
        for (int ks = 0; ks < 5; ++ks) {
            short8b Bf[2];
            #pragma unroll
            for (int rr = 0; rr < 2; ++rr) {
                const unsigned char* bp = (ks == 4 && gh)
                    ? (const unsigned char*)(zreg + gl * 8)
                    : (const unsigned char*)xl + ((r0 + rr) * 18 + nn) * 32 + off[ks];
                Bf[rr] = *(const short8b*)bp;
            }
            #pragma unroll
            for (int mt = 0; mt < 4; ++mt) {
                acc[mt][0] = __builtin_amdgcn_mfma_f32_16x16x32_bf16(aW1[mt][ks], Bf[0], acc[mt][0], 0, 0, 0);
                acc[mt][1] = __builtin_amdgcn_mfma_f32_16x16x32_bf16(aW1[mt][ks], Bf[1], acc[mt][1], 0, 0, 0);
            }
        }

        // drain both rows' h (relu + cvt_pk) into phasebuf phs&1
        unsigned char* hpb = hb_p + (phs & 1) * 8192;
        #pragma unroll
        for (int rr = 0; rr < 2; ++rr) {
            unsigned char* slab = hpb + rr * 4096;
            #pragma unroll
            for (int mt = 0; mt < 4; ++mt) {
                uint2 u;
                u.x = cvtpk_bf16(fmaxf(acc[mt][rr][0], 0.f), fmaxf(acc[mt][rr][1], 0.f));
                u.y = cvtpk_bf16(fmaxf(acc[mt][rr][2], 0.f), fmaxf(acc[mt][rr][3], 0.f));
                const int wb = (nn << 8) + ((64 * q + 16 * mt + 4 * g) << 1);
                *(uint2*)(slab + (wb ^ xmask)) = u;
            }
        }

        __syncthreads();   // h(phase) visible; phasebuf reuse fenced by next barrier

        // layer-2 for both rows by alternating worker; other wave runs ahead
        if (q == (phs & 1)) {
            #pragma unroll
            for (int rr = 0; rr < 2; ++rr) {
                const unsigned char* slab = hpb + rr * 4096;
                f32x4 a2 = (f32x4)0.f;
                #pragma unroll
                for (int ks2 = 0; ks2 < 4; ++ks2) {
                    const int rb = (nn << 8) + ((32 * ks2 + 8 * g) << 1);
                    const short8b bh = *(const short8b*)(slab + (rb ^ xmask));
                    a2 = __builtin_amdgcn_mfma_f32_16x16x32_bf16(aW2[ks2], bh, a2, 0, 0, 0);
                }
                const int oi = i0 + r0 + rr, oj = j0 + nn;
                float* op = out + ((size_t)(b * CIN + 4 * g) * HH + oi) * WW + oj;
                #pragma unroll
                for (int r = 0; r < 4; ++r)
                    op[(size_t)r * HH * WW] = a2[r];
            }
        }
    }
}

// ---------- middle tier: proven v8 (x from NCHW f32, scalar staging) ----------
#define SM6_XL  0
#define SM6_HB  19584
#define SM6_ZR  35968
#define SM6_TOT 36000

__global__ __launch_bounds__(256, 2) void updatenet_v8m(
    const float* __restrict__ x,
    const unsigned short* __restrict__ ws,
    float* __restrict__ out)
{
    __shared__ __align__(16) unsigned char smem[SM6_TOT];
    unsigned short* xl   = (unsigned short*)(smem + SM6_XL);
    unsigned short* zreg = (unsigned short*)(smem + SM6_ZR);

    const int b  = blockIdx.z;
    const int i0 = blockIdx.y * 32;
    const int j0 = blockIdx.x * 16;
    const int t  = threadIdx.x;

    {
        const size_t cs = (size_t)HH * WW;
        for (int pidx = t; pidx < 34 * 18; pidx += 256) {
            const int ri = pidx / 18, rj = pidx % 18;
            const int ii = i0 + ri - 1, jj = j0 + rj - 1;
            const bool ok = (ii >= 0) & (ii < HH) & (jj >= 0) & (jj < WW);
            const float* xp = x + ((size_t)b * CIN * HH + ii) * WW + jj;
            short8b s0, s1;
            #pragma unroll
            for (int c = 0; c < 8; ++c) {
                s0[c] = ok ? (short)f2bf(xp[c * cs]) : (short)0;
                s1[c] = ok ? (short)f2bf(xp[(c + 8) * cs]) : (short)0;
            }
            *(short8b*)(xl + pidx * 16)     = s0;
            *(short8b*)(xl + pidx * 16 + 8) = s1;
        }
        if (t < 2) *(short8b*)(zreg + t * 8) = (short8b)0;
    }

    const int wv   = t >> 6;
    const int lane = t & 63;
    const int p    = wv >> 1;
    const int q    = wv & 1;
    const int g    = lane >> 4;
    const int nn   = lane & 15;
    const int gh   = g >> 1, gl = g & 1;

    short8b aW1[4][5];
    #pragma unroll
    for (int mt = 0; mt < 4; ++mt)
        #pragma unroll
        for (int ks = 0; ks < 5; ++ks) {
            const int ak = (ks == 4) ? (128 + 8 * gl) : (32 * ks + 8 * g);
            aW1[mt][ks] = *(const short8b*)(ws + (size_t)(64 * q + 16 * mt + nn) * KEFF + ak);
        }
    short8b aW2[4];
    #pragma unroll
    for (int ks = 0; ks < 4; ++ks)
        aW2[ks] = *(const short8b*)(ws + HID * KEFF + nn * HID + 32 * ks + 8 * g);

    int off[5];
    #pragma unroll
    for (int ks = 0; ks < 5; ++ks) {
        int tap = 2 * ks + gh;
        if (tap > 8) tap = 8;
        off[ks] = ((tap / 3) * 18 + (tap % 3)) * 32 + gl * 16;
    }

    unsigned char* hb_pair = smem + SM6_HB + p * 8192;
    const int xmask = (nn & 7) << 4;

    __syncthreads();

    for (int s = 0; s < 16; ++s) {
        const int row = 16 * p + s;
        const unsigned char* xbase = (const unsigned char*)xl + (row * 18 + nn) * 32;

        f32x4 acc[4];
        #pragma unroll
        for (int mt = 0; mt < 4; ++mt) acc[mt] = (f32x4)0.f;

        #pragma unroll
        for (int ks = 0; ks < 5; ++ks) {
            const unsigned char* bp = (ks == 4 && gh) ? (const unsigned char*)(zreg + gl * 8)
                                                      : xbase + off[ks];
            const short8b bfrag = *(const short8b*)bp;
            #pragma unroll
            for (int mt = 0; mt < 4; ++mt)
                acc[mt] = __builtin_amdgcn_mfma_f32_16x16x32_bf16(aW1[mt][ks], bfrag, acc[mt], 0, 0, 0);
        }

        unsigned char* hph = hb_pair + (s & 1) * 4096;
        #pragma unroll
        for (int mt = 0; mt < 4; ++mt) {
            const unsigned int lo = (unsigned int)f2bf(fmaxf(acc[mt][0], 0.f))
                                  | ((unsigned int)f2bf(fmaxf(acc[mt][1], 0.f)) << 16);
            const unsigned int hi = (unsigned int)f2bf(fmaxf(acc[mt][2], 0.f))
                                  | ((unsigned int)f2bf(fmaxf(acc[mt][3], 0.f)) << 16);
            uint2 u; u.x = lo; u.y = hi;
            const int wb = (nn << 8) + ((64 * q + 16 * mt + 4 * g) << 1);
            *(uint2*)(hph + (wb ^ xmask)) = u;
        }

        __syncthreads();

        if (q == (s & 1)) {
            f32x4 a2 = (f32x4)0.f;
            #pragma unroll
            for (int ks2 = 0; ks2 < 4; ++ks2) {
                const int rb = (nn << 8) + ((32 * ks2 + 8 * g) << 1);
                const short8b bh = *(const short8b*)(hph + (rb ^ xmask));
                a2 = __builtin_amdgcn_mfma_f32_16x16x32_bf16(aW2[ks2], bh, a2, 0, 0, 0);
            }
            const int oi = i0 + row, oj = j0 + nn;
            float* op = out + ((size_t)(b * CIN + 4 * g) * HH + oi) * WW + oj;
            #pragma unroll
            for (int r = 0; r < 4; ++r)
                op[(size_t)r * HH * WW] = a2[r];
        }
    }
}

// ---------- last tier: no-ws fallback (round-4 proven) ----------
#define SM_WEFF  0
#define SM_GUARD 36864
#define SM_W2B   36880
#define SM_XL    41232
#define SM_ZREG  60816
#define SM_HALL  60848
#define SM_TOTAL 78256

__global__ __launch_bounds__(256, 2) void updatenet_fallback(
    const float* __restrict__ x, const float* __restrict__ w1f,
    const float* __restrict__ w2f, float* __restrict__ out)
{
    __shared__ __align__(16) unsigned char smem[SM_TOTAL];
    unsigned short* weff = (unsigned short*)(smem + SM_WEFF);
    unsigned short* w2b  = (unsigned short*)(smem + SM_W2B);
    unsigned short* xl   = (unsigned short*)(smem + SM_XL);
    unsigned short* zreg = (unsigned short*)(smem + SM_ZREG);

    const int b  = blockIdx.z;
    const int i0 = blockIdx.y * 32;
    const int j0 = blockIdx.x * 16;
    const int t  = threadIdx.x;

    for (int idx = t; idx < HID * KEFF; idx += 256) {
        const float SX[9] = {-1.f, 0.f, 1.f, -2.f, 0.f, 2.f, -1.f, 0.f, 1.f};
        const float SY[9] = {-1.f, -2.f, -1.f, 0.f, 0.f, 0.f, 1.f, 2.f, 1.f};
        const int o = idx / KEFF, r = idx % KEFF;
        const int tap = r >> 4, cc = r & 15;
        float v = w1f[o * 48 + 16 + cc] * SX[tap] + w1f[o * 48 + 32 + cc] * SY[tap];
        if (tap == 4) v += w1f[o * 48 + cc];
        weff[idx] = f2bf(v);
    }
    for (int idx = t; idx < CIN * HID; idx += 256)
        w2b[(idx >> 7) * 136 + (idx & 127)] = f2bf(w2f[idx]);

    {
        const size_t cs = (size_t)HH * WW;
        for (int pp = t; pp < 34 * 18; pp += 256) {
            const int ri = pp / 18, rj = pp % 18;
            const int ii = i0 + ri - 1, jj = j0 + rj - 1;
            const bool ok = (ii >= 0) & (ii < HH) & (jj >= 0) & (jj < WW);
            const float* xp = x + ((size_t)b * CIN * HH + ii) * WW + jj;
            short8b s0, s1;
            #pragma unroll
            for (int c = 0; c < 8; ++c) {
                s0[c] = ok ? (short)f2bf(xp[c * cs]) : (short)0;
                s1[c] = ok ? (short)f2bf(xp[(c + 8) * cs]) : (short)0;
            }
            *(short8b*)(xl + pp * 16)     = s0;
            *(short8b*)(xl + pp * 16 + 8) = s1;
        }
        if (t < 2) *(short8b*)(zreg + t * 8) = (short8b)0;
        if (t == 2) *(short8b*)(smem + SM_GUARD) = (short8b)0;
    }
    __syncthreads();

    const int w = t >> 6, lane = t & 63;
    const int g = lane >> 4, nn = lane & 15;
    const int gh = g >> 1, gl = g & 1;

    short8b aW1[8][5];
    #pragma unroll
    for (int m = 0; m < 8; ++m)
        #pragma unroll
        for (int ks = 0; ks < 5; ++ks) {
            const int ak = (ks == 4) ? (128 + 8 * gl) : (32 * ks + 8 * g);
            aW1[m][ks] = *(const short8b*)(weff + (16 * m + nn) * KEFF + ak);
        }

    int off[5];
    #pragma unroll
    for (int ks = 0; ks < 5; ++ks) {
        int tap = 2 * ks + gh;
        if (tap > 8) tap = 8;
        off[ks] = ((tap / 3) * 18 + (tap % 3)) * 32 + gl * 16;
    }

    unsigned short* hb = (unsigned short*)(smem + SM_HALL) + w * (16 * 136);

    for (int nt = 0; nt < 8; ++nt) {
        const int i = 8 * w + nt;
        const unsigned char* xbase = (const unsigned char*)xl + (i * 18 + nn) * 32;
        f32x4 acc[8];
        #pragma unroll
        for (int m = 0; m < 8; ++m) acc[m] = (f32x4)0.f;
        #pragma unroll
        for (int ks = 0; ks < 5; ++ks) {
            const unsigned char* bp = (ks == 4 && gh) ? (const unsigned char*)(zreg + gl * 8)
                                                      : xbase + off[ks];
            const short8b bfrag = *(const short8b*)bp;
            #pragma unroll
            for (int m = 0; m < 8; ++m)
                acc[m] = __builtin_amdgcn_mfma_f32_16x16x32_bf16(aW1[m][ks], bfrag, acc[m], 0, 0, 0);
        }
        #pragma unroll
        for (int m = 0; m < 8; ++m) {
            const unsigned int lo = (unsigned int)f2bf(fmaxf(acc[m][0], 0.f))
                                  | ((unsigned int)f2bf(fmaxf(acc[m][1], 0.f)) << 16);
            const unsigned int hi = (unsigned int)f2bf(fmaxf(acc[m][2], 0.f))
                                  | ((unsigned int)f2bf(fmaxf(acc[m][3], 0.f)) << 16);
            uint2 u; u.x = lo; u.y = hi;
            *(uint2*)(hb + nn * 136 + 16 * m + 4 * g) = u;
        }
        asm volatile("s_waitcnt lgkmcnt(0)" ::: "memory");
        f32x4 a2 = (f32x4)0.f;
        #pragma unroll
        for (int ks = 0; ks < 4; ++ks) {
            const short8b aw2 = *(const short8b*)(w2b + nn * 136 + 32 * ks + 8 * g);
            const short8b bh  = *(const short8b*)(hb + nn * 136 + 32 * ks + 8 * g);
            a2 = __builtin_amdgcn_mfma_f32_16x16x32_bf16(aw2, bh, a2, 0, 0, 0);
        }
        const int oi = i0 + i, oj = j0 + nn;
        float* op = out + ((size_t)(b * CIN + 4 * g) * HH + oi) * WW + oj;
        #pragma unroll
        for (int r = 0; r < 4; ++r)
            op[(size_t)r * HH * WW] = a2[r];
    }
}

extern "C" void kernel_launch(void* const* d_in, const int* in_sizes, int n_in,
                              void* d_out, int out_size, void* d_ws, size_t ws_size,
                              hipStream_t stream) {
    const float* x  = (const float*)d_in[0];
    const float* w1 = (const float*)d_in[1];
    const float* w2 = (const float*)d_in[2];
    float* out = (float*)d_out;

    const int Bn = in_sizes[0] / (CIN * HH * WW);   // 32
    dim3 grid(WW / 16, HH / 32, Bn);                // 4096 blocks

    const size_t x2_bytes = (size_t)Bn * CIN * HH * WW * 2;   // 67.1 MB

    if (ws_size >= (size_t)WS_W_BYTES + x2_bytes) {
        unsigned short* ws = (unsigned short*)d_ws;
        build_weff<<<(HID * KEFF + CIN * HID + 255) / 256, 256, 0, stream>>>(w1, w2, ws);
        nchw_to_nhwc<<<Bn * HH, 256, 0, stream>>>(x, ws + X2_OFF_SHORTS);
        updatenet_v15<<<grid, 256, 0, stream>>>(ws, out);
    } else if (ws_size >= (size_t)WS_W_BYTES) {
        unsigned short* ws = (unsigned short*)d_ws;
        build_weff<<<(HID * KEFF + CIN * HID + 255) / 256, 256, 0, stream>>>(w1, w2, ws);
        updatenet_v8m<<<grid, 256, 0, stream>>>(x, ws, out);
    } else {
        updatenet_fallback<<<grid, 256, 0, stream>>>(x, w1, w2, out);
    }
}